// Round 11
// baseline (1260.081 us; speedup 1.0000x reference)
//
#include <hip/hip_runtime.h>

// RSNEncoder R11: R10 structure verbatim, MFMA swapped to 32x32x16 bf16
// (4060 FLOP/cyc vs 3378 for 16x16x32, m119): per-CU MFMA cyc/tile 1862->1549.
// Fragment reads identical count/bytes; bank pattern still minimum-8-pass.
// C/D layout (m74/m101): col=lane&31, row=(j&3)+8*(j>>2)+4*(lane>>5).

#define BDIM 32768
#define DDIM 512
#define BD (BDIM * DDIM)

typedef short bf16x8 __attribute__((ext_vector_type(8)));
typedef float f32x16 __attribute__((ext_vector_type(16)));
typedef unsigned short u16x8 __attribute__((ext_vector_type(8)));

#define AS1 __attribute__((address_space(1)))
#define AS3 __attribute__((address_space(3)))

__device__ __forceinline__ unsigned short f2bf(float f) {
  union { float f; unsigned u; } v; v.f = f;
  return (unsigned short)((v.u + 0x7fffu + ((v.u >> 16) & 1u)) >> 16);  // RNE
}
__device__ __forceinline__ float bf2f(unsigned short b) {
  union { unsigned u; float f; } v; v.u = (unsigned)b << 16; return v.f;
}
__device__ __forceinline__ float sigmf(float x) { return 1.0f / (1.0f + __expf(-x)); }
__device__ __forceinline__ float tanhf_(float x) { return 1.0f - 2.0f / (__expf(2.0f * x) + 1.0f); }
__device__ __forceinline__ void bar() { asm volatile("s_barrier" ::: "memory"); }
#define VMCNT(n) asm volatile("s_waitcnt vmcnt(" #n ")" ::: "memory")

template <int N> struct ICt { static constexpr int v = N; };

// ---- fp32 -> bf16 (all of x) ----
__global__ void cvt_bf16_all(const float* __restrict__ in, unsigned short* __restrict__ out) {
  const size_t stride = (size_t)gridDim.x * 256;
  for (size_t i = (size_t)blockIdx.x * 256 + threadIdx.x; i < (size_t)BD; i += stride) {
    const size_t o = i * 8;
    const float4 a = *(const float4*)(in + o);
    const float4 b = *(const float4*)(in + o + 4);
    u16x8 v;
    v[0] = f2bf(a.x); v[1] = f2bf(a.y); v[2] = f2bf(a.z); v[3] = f2bf(a.w);
    v[4] = f2bf(b.x); v[5] = f2bf(b.y); v[6] = f2bf(b.z); v[7] = f2bf(b.w);
    *(u16x8*)(out + o) = v;
  }
}

// ---- weight prep: Wg[1536][1024] = [Wih | Whh]; Wm[512][1024] = [w1 | w2] ----
__global__ void prep_w(const float* __restrict__ wih, const float* __restrict__ whh,
                       const float* __restrict__ w1, const float* __restrict__ w2,
                       unsigned short* __restrict__ Wg, unsigned short* __restrict__ Wm) {
  int i = blockIdx.x * 256 + threadIdx.x;
  if (i < 1536 * 1024) {
    const int j = i >> 10, k = i & 1023;
    Wg[i] = f2bf((k < 512) ? wih[j * 512 + k] : whh[j * 512 + (k - 512)]);
  } else {
    i -= 1536 * 1024;
    const int j = i >> 10, k = i & 1023;
    Wm[i] = f2bf((k < 512) ? w1[j * 512 + k] : w2[j * 512 + (k - 512)]);
  }
}

// ================= gates kernel =================
// Block 128 rows x 64 d (192 gate-cols); 4 waves 2m x 2n; wave 64 x 96.
// LDS: 2 bufs x (A 16KB + B 24KB) = 80KB -> 2 blocks/CU.
// acc[mf][set]: set 0=r 1=z 2=i_n 3=h_n; 32x32 frags (mf in {0,1}, gate g nf).
__global__ __launch_bounds__(256, 2) void gru_gates(
    const unsigned short* __restrict__ X, const unsigned short* __restrict__ H,
    const unsigned short* __restrict__ Wg, const float* __restrict__ bih,
    const float* __restrict__ bhh, unsigned short* __restrict__ outB) {
  __shared__ char smem[81920];
  const int t = threadIdx.x;
  const int lane = t & 63, wid = t >> 6;
  const int wm = wid >> 1, wn = wid & 1;
  const int xcd = blockIdx.x & 7, ixc = blockIdx.x >> 3;
  const int bm = xcd * 32 + (ixc >> 3);  // 256 m-blocks of 128 rows
  const int bn = ixc & 7;                // 8 d-blocks

  f32x16 acc[2][4];
#pragma unroll
  for (int a = 0; a < 2; ++a)
#pragma unroll
    for (int b = 0; b < 4; ++b) acc[a][b] = (f32x16)(0.0f);

  // staging source offsets (pre-swizzled col slot; rule #21); 4KB per call
  const int trow = t >> 3;
  const int tswz = ((t & 7) * 16) ^ ((trow & 7) << 4);
  int asrc[4], bsrc[6];
#pragma unroll
  for (int i = 0; i < 4; ++i) asrc[i] = (bm * 128 + i * 32 + trow) * 1024 + tswz;
#pragma unroll
  for (int j = 0; j < 6; ++j)
    bsrc[j] = ((j >> 1) * 512 + bn * 64 + (j & 1) * 32 + trow) * 2048 + tswz;

  const char* Xc = (const char*)X;
  const char* Hc = (const char*)H;
  const char* Wc = (const char*)Wg;

  auto stage = [&](int tt) {  // full tile tt -> buf tt&1 (A 4 + B 6 issues)
    const char* Ab = ((tt < 8) ? Xc : Hc) + (tt & 7) * 128;
    const char* Bb = Wc + tt * 128;
    char* dst = smem + (tt & 1) * 40960;
#pragma unroll
    for (int i = 0; i < 4; ++i)
      __builtin_amdgcn_global_load_lds((const AS1 void*)(Ab + asrc[i]),
                                       (AS3 void*)(dst + i * 4096 + t * 16), 16, 0, 0);
#pragma unroll
    for (int j = 0; j < 6; ++j)
      __builtin_amdgcn_global_load_lds((const AS1 void*)(Bb + bsrc[j]),
                                       (AS3 void*)(dst + 16384 + j * 4096 + t * 16), 16, 0, 0);
  };

  // 32x32 fragment addressing: row = base + (lane&31), kbyte = ks*32 + (lane>>5)*16
  const int ar0 = wm * 64 + (lane & 31);
  const int kc0 = (lane >> 5) * 16;

  auto do_tile = [&](int kt, auto nsel) {
    constexpr int NS = decltype(nsel)::v;  // n-gate acc set: 2 (i_n) or 3 (h_n)
    VMCNT(0);  // own stage loads for tile kt arrived
    bar();     // all waves' stages arrived; prior-tile reads retired
    if (kt + 1 < 16) stage(kt + 1);
    const char* pa = smem + (kt & 1) * 40960;
    const char* pb = pa + 16384;
#pragma unroll
    for (int ks = 0; ks < 4; ++ks) {  // K16 steps
      bf16x8 av[2], bv[3];
      const int cb = ks * 32 + kc0;
#pragma unroll
      for (int mf = 0; mf < 2; ++mf) {
        const int r = ar0 + mf * 32;
        av[mf] = *(const bf16x8*)(pa + r * 128 + (cb ^ ((r & 7) << 4)));
      }
#pragma unroll
      for (int g = 0; g < 3; ++g) {
        const int r = g * 64 + wn * 32 + (lane & 31);
        bv[g] = *(const bf16x8*)(pb + r * 128 + (cb ^ ((r & 7) << 4)));
      }
      __builtin_amdgcn_s_setprio(1);
#pragma unroll
      for (int g = 0; g < 3; ++g) {
        const int set = (g < 2) ? g : NS;  // compile-time (g unrolled)
#pragma unroll
        for (int mf = 0; mf < 2; ++mf)
          acc[mf][set] = __builtin_amdgcn_mfma_f32_32x32x16_bf16(av[mf], bv[g],
                                                                acc[mf][set], 0, 0, 0);
      }
      __builtin_amdgcn_s_setprio(0);
    }
  };

  stage(0);
  for (int kt = 0; kt < 8; ++kt) do_tile(kt, ICt<2>{});       // K<512: i_n
  for (int kt = 8; kt < 16; ++kt) do_tile(kt, ICt<3>{});      // K>=512: h_n

  // epilogue: 32x32 C/D map col=lane&31, row=(j&3)+8*(j>>2)+4*(lane>>5)
  const int d = bn * 64 + wn * 32 + (lane & 31);
  const float br = bih[d] + bhh[d];
  const float bz = bih[512 + d] + bhh[512 + d];
  const float bi = bih[1024 + d];
  const float bh = bhh[1024 + d];
  const int rl0 = 4 * (lane >> 5);
#pragma unroll
  for (int mf = 0; mf < 2; ++mf) {
#pragma unroll
    for (int j = 0; j < 16; ++j) {
      const int row = bm * 128 + wm * 64 + mf * 32 + (j & 3) + 8 * (j >> 2) + rl0;
      const size_t off = (size_t)row * 512 + d;
      const float rv = sigmf(acc[mf][0][j] + br);
      const float zv = sigmf(acc[mf][1][j] + bz);
      const float nv = tanhf_(acc[mf][2][j] + bi + rv * (acc[mf][3][j] + bh));
      outB[off] = f2bf((1.0f - zv) * nv + zv * bf2f(H[off]));
    }
  }
}

// ================= mixed kernel: out = [h | x_prev] @ [w1|w2]^T =================
// Block 128 x 128; 4 waves 2m x 2n; wave 64 x 64 (2x2 32x32 frags).
// LDS 2 x 32KB = 64KB -> 2 blocks/CU.
template <int WF>
__global__ __launch_bounds__(256, 2) void mixed_gemm(
    const unsigned short* __restrict__ Ka, const unsigned short* __restrict__ Kb,
    const unsigned short* __restrict__ Wm,
    unsigned short* __restrict__ outB, float* __restrict__ outF) {
  __shared__ char smem[65536];
  const int t = threadIdx.x;
  const int lane = t & 63, wid = t >> 6;
  const int wm = wid >> 1, wn = wid & 1;
  const int xcd = blockIdx.x & 7, ixc = blockIdx.x >> 3;  // grid 1024
  const int bm = xcd * 32 + (ixc >> 2);  // 256 m-blocks
  const int bn = ixc & 3;                // 4 n-blocks of 128

  f32x16 acc[2][2];
#pragma unroll
  for (int a = 0; a < 2; ++a)
#pragma unroll
    for (int b = 0; b < 2; ++b) acc[a][b] = (f32x16)(0.0f);

  const int trow = t >> 3;
  const int tswz = ((t & 7) * 16) ^ ((trow & 7) << 4);
  int asrc[4], bsrc[4];
#pragma unroll
  for (int i = 0; i < 4; ++i) {
    asrc[i] = (bm * 128 + i * 32 + trow) * 1024 + tswz;
    bsrc[i] = (bn * 128 + i * 32 + trow) * 2048 + tswz;
  }
  const char* Kac = (const char*)Ka;
  const char* Kbc = (const char*)Kb;
  const char* Wc = (const char*)Wm;

  auto stage = [&](int tt) {
    const char* Ab = ((tt < 8) ? Kac : Kbc) + (tt & 7) * 128;
    const char* Bb = Wc + tt * 128;
    char* dst = smem + (tt & 1) * 32768;
#pragma unroll
    for (int i = 0; i < 4; ++i)
      __builtin_amdgcn_global_load_lds((const AS1 void*)(Ab + asrc[i]),
                                       (AS3 void*)(dst + i * 4096 + t * 16), 16, 0, 0);
#pragma unroll
    for (int j = 0; j < 4; ++j)
      __builtin_amdgcn_global_load_lds((const AS1 void*)(Bb + bsrc[j]),
                                       (AS3 void*)(dst + 16384 + j * 4096 + t * 16), 16, 0, 0);
  };

  const int ar0 = wm * 64 + (lane & 31);
  const int br0 = wn * 64 + (lane & 31);
  const int kc0 = (lane >> 5) * 16;

  stage(0);
  for (int kt = 0; kt < 16; ++kt) {
    VMCNT(0);
    bar();
    if (kt + 1 < 16) stage(kt + 1);
    const char* pa = smem + (kt & 1) * 32768;
    const char* pb = pa + 16384;
#pragma unroll
    for (int ks = 0; ks < 4; ++ks) {
      bf16x8 av[2], bv[2];
      const int cb = ks * 32 + kc0;
#pragma unroll
      for (int mf = 0; mf < 2; ++mf) {
        const int r = ar0 + mf * 32;
        av[mf] = *(const bf16x8*)(pa + r * 128 + (cb ^ ((r & 7) << 4)));
      }
#pragma unroll
      for (int nf = 0; nf < 2; ++nf) {
        const int r = br0 + nf * 32;
        bv[nf] = *(const bf16x8*)(pb + r * 128 + (cb ^ ((r & 7) << 4)));
      }
      __builtin_amdgcn_s_setprio(1);
#pragma unroll
      for (int nf = 0; nf < 2; ++nf)
#pragma unroll
        for (int mf = 0; mf < 2; ++mf)
          acc[mf][nf] = __builtin_amdgcn_mfma_f32_32x32x16_bf16(av[mf], bv[nf],
                                                               acc[mf][nf], 0, 0, 0);
      __builtin_amdgcn_s_setprio(0);
    }
  }

  const int rl0 = 4 * (lane >> 5);
#pragma unroll
  for (int mf = 0; mf < 2; ++mf)
#pragma unroll
    for (int nf = 0; nf < 2; ++nf) {
      const int col = bn * 128 + wn * 64 + nf * 32 + (lane & 31);
#pragma unroll
      for (int j = 0; j < 16; ++j) {
        const int row = bm * 128 + wm * 64 + mf * 32 + (j & 3) + 8 * (j >> 2) + rl0;
        const size_t off = (size_t)row * 512 + col;
        const float v = acc[mf][nf][j];
        if constexpr (WF) outF[off] = v;
        else              outB[off] = f2bf(v);
      }
    }
}

extern "C" void kernel_launch(void* const* d_in, const int* in_sizes, int n_in,
                              void* d_out, int out_size, void* d_ws, size_t ws_size,
                              hipStream_t stream) {
  const float* x   = (const float*)d_in[0];
  const float* wih = (const float*)d_in[1];
  const float* whh = (const float*)d_in[2];
  const float* bih = (const float*)d_in[3];
  const float* bhh = (const float*)d_in[4];
  const float* w1  = (const float*)d_in[5];
  const float* w2  = (const float*)d_in[6];

  char* ws = (char*)d_ws;
  const size_t bd2 = (size_t)BD * 2;
  unsigned short* xall  = (unsigned short*)ws;                  // 8 x 32 MB
  unsigned short* hb[2] = {(unsigned short*)(ws + 8 * bd2),
                           (unsigned short*)(ws + 9 * bd2)};    // 32 MB each
  unsigned short* Wg = (unsigned short*)(ws + 10 * bd2);        // 3 MB
  unsigned short* Wm = Wg + 1536 * 1024;                        // 1 MB

  hipMemsetAsync(hb[0], 0, bd2, stream);  // h0 = 0
  cvt_bf16_all<<<2048, 256, 0, stream>>>(x, xall);
  prep_w<<<8192, 256, 0, stream>>>(wih, whh, w1, w2, Wg, Wm);

  int hp = 0;
  for (int i = 0; i < 8; ++i) {
    const unsigned short* xi = xall + (size_t)i * BD;
    gru_gates<<<2048, 256, 0, stream>>>(xi, hb[hp], Wg, bih, bhh, hb[hp ^ 1]);
    hp ^= 1;
    if (i & 1) {
      const unsigned short* xprev = xall + (size_t)(i - 1) * BD;
      if (i == 7)
        mixed_gemm<1><<<1024, 256, 0, stream>>>(hb[hp], xprev, Wm, nullptr, (float*)d_out);
      else
        mixed_gemm<0><<<1024, 256, 0, stream>>>(hb[hp], xprev, Wm, hb[hp ^ 1], nullptr);
      if (i != 7) hp ^= 1;
    }
  }
}

// Round 12
// 1180.328 us; speedup vs baseline: 1.0676x; 1.0676x over previous
//
#include <hip/hip_runtime.h>

// RSNEncoder R12: R10 GEMM structure (best, 1194us) with:
//  (1) no x pre-conversion: X-halves reg-staged straight from f32 x
//      (early global_load_dwordx4 -> v_cvt_pk_bf16_f32 -> swizzled ds_write),
//  (2) step-0 gates specialization (h=0): 8 K-tiles only, no H access.
// Removes the 118us cvt kernel (768MB HBM round-trip) and half of step-0.

#define BDIM 32768
#define DDIM 512
#define BD (BDIM * DDIM)

typedef short bf16x8 __attribute__((ext_vector_type(8)));
typedef float f32x4 __attribute__((ext_vector_type(4)));

#define AS1 __attribute__((address_space(1)))
#define AS3 __attribute__((address_space(3)))

__device__ __forceinline__ unsigned short f2bf(float f) {
  union { float f; unsigned u; } v; v.f = f;
  return (unsigned short)((v.u + 0x7fffu + ((v.u >> 16) & 1u)) >> 16);  // RNE
}
__device__ __forceinline__ float bf2f(unsigned short b) {
  union { unsigned u; float f; } v; v.u = (unsigned)b << 16; return v.f;
}
__device__ __forceinline__ float sigmf(float x) { return 1.0f / (1.0f + __expf(-x)); }
__device__ __forceinline__ float tanhf_(float x) { return 1.0f - 2.0f / (__expf(2.0f * x) + 1.0f); }
__device__ __forceinline__ void bar() { asm volatile("s_barrier" ::: "memory"); }
#define LGKM0 asm volatile("s_waitcnt lgkmcnt(0)" ::: "memory")
#define VMCNT(n) asm volatile("s_waitcnt vmcnt(" #n ")" ::: "memory")

__device__ __forceinline__ unsigned cvtpk(float lo, float hi) {
  unsigned r;
  asm("v_cvt_pk_bf16_f32 %0, %1, %2" : "=v"(r) : "v"(lo), "v"(hi));
  return r;
}

template <int N> struct ICt { static constexpr int v = N; };

// ---- weight prep: Wg[1536][1024] = [Wih | Whh]; Wm[512][1024] = [w1 | w2] ----
__global__ void prep_w(const float* __restrict__ wih, const float* __restrict__ whh,
                       const float* __restrict__ w1, const float* __restrict__ w2,
                       unsigned short* __restrict__ Wg, unsigned short* __restrict__ Wm) {
  int i = blockIdx.x * 256 + threadIdx.x;
  if (i < 1536 * 1024) {
    const int j = i >> 10, k = i & 1023;
    Wg[i] = f2bf((k < 512) ? wih[j * 512 + k] : whh[j * 512 + (k - 512)]);
  } else {
    i -= 1536 * 1024;
    const int j = i >> 10, k = i & 1023;
    Wm[i] = f2bf((k < 512) ? w1[j * 512 + k] : w2[j * 512 + (k - 512)]);
  }
}

// ================= gates kernel =================
// Block 128 rows x 64 d (192 gate-cols); 4 waves 2m x 2n; wave 64 x 96.
// LDS: 2 bufs x (A 16KB + B 24KB) = 80KB -> 2 blocks/CU.
// K-tiles: kt<8 = x (f32 reg-staged), kt>=8 = h (bf16 DMA). FIRST=1: 8 tiles only.
// acc[fm][ai]: ai 0,1=r  2,3=z  4,5=i_n  6,7=h_n.
template <int FIRST>
__global__ __launch_bounds__(256, 2) void gru_gates(
    const float* __restrict__ Xf, const unsigned short* __restrict__ H,
    const unsigned short* __restrict__ Wg, const float* __restrict__ bih,
    const float* __restrict__ bhh, unsigned short* __restrict__ outB) {
  __shared__ char smem[81920];
  constexpr int NT = FIRST ? 8 : 16;
  const int t = threadIdx.x;
  const int lane = t & 63, wid = t >> 6;
  const int wm = wid >> 1, wn = wid & 1;
  const int xcd = blockIdx.x & 7, ixc = blockIdx.x >> 3;
  const int bm = xcd * 32 + (ixc >> 3);  // 256 m-blocks of 128 rows
  const int bn = ixc & 7;                // 8 d-blocks

  f32x4 acc[4][8];
  const f32x4 z4 = {0.f, 0.f, 0.f, 0.f};
#pragma unroll
  for (int a = 0; a < 4; ++a)
#pragma unroll
    for (int b = 0; b < 8; ++b) acc[a][b] = z4;

  const int trow = t >> 3;                                     // 0..31
  const int tswz = ((t & 7) * 16) ^ ((trow & 7) << 4);
  int hsrc[4], bsrc[6], ldsx[4], xsrc[4];
#pragma unroll
  for (int i = 0; i < 4; ++i) {
    hsrc[i] = (bm * 128 + i * 32 + trow) * 1024 + tswz;        // h bf16 DMA (pre-swz src)
    xsrc[i] = (bm * 128 + i * 32 + trow) * 2048 + (t & 7) * 32; // x f32 (linear src)
    ldsx[i] = (i * 32 + trow) * 128 + tswz;                    // swizzled LDS dest
  }
#pragma unroll
  for (int j = 0; j < 6; ++j)
    bsrc[j] = ((j >> 1) * 512 + bn * 64 + (j & 1) * 32 + trow) * 2048 + tswz;

  const char* Xc = (const char*)Xf;
  const char* Hc = (const char*)H;
  const char* Wc = (const char*)Wg;

  auto stageB = [&](int tt) {
    const char* Bb = Wc + tt * 128;
    char* dst = smem + (tt & 1) * 40960 + 16384;
#pragma unroll
    for (int j = 0; j < 6; ++j)
      __builtin_amdgcn_global_load_lds((const AS1 void*)(Bb + bsrc[j]),
                                       (AS3 void*)(dst + j * 4096 + t * 16), 16, 0, 0);
  };
  auto stageAH = [&](int tt) {  // h half (tt >= 8)
    const char* Ab = Hc + (tt & 7) * 128;
    char* dst = smem + (tt & 1) * 40960;
#pragma unroll
    for (int i = 0; i < 4; ++i)
      __builtin_amdgcn_global_load_lds((const AS1 void*)(Ab + hsrc[i]),
                                       (AS3 void*)(dst + i * 4096 + t * 16), 16, 0, 0);
  };

  float4 xv[4][2];
  auto loadX = [&](int tt) {  // x half (tt < 8): 8 f32 per thread-issue
#pragma unroll
    for (int i = 0; i < 4; ++i) {
      const char* p = Xc + xsrc[i] + tt * 256;
      xv[i][0] = *(const float4*)p;
      xv[i][1] = *(const float4*)(p + 16);
    }
  };
  auto writeX = [&](int tt) {  // cvt + swizzled ds_write
    char* dst = smem + (tt & 1) * 40960;
#pragma unroll
    for (int i = 0; i < 4; ++i) {
      int4 w;
      w.x = (int)cvtpk(xv[i][0].x, xv[i][0].y);
      w.y = (int)cvtpk(xv[i][0].z, xv[i][0].w);
      w.z = (int)cvtpk(xv[i][1].x, xv[i][1].y);
      w.w = (int)cvtpk(xv[i][1].z, xv[i][1].w);
      *(int4*)(dst + ldsx[i]) = w;
    }
  };

  const int ar0 = wm * 64 + (lane & 15);
  const int kc0 = (lane >> 4) * 16;

  auto do_tile = [&](int kt, auto nsel) {
    constexpr int NS = decltype(nsel)::v;  // n-gate acc base: 4 (i_n) or 6 (h_n)
    VMCNT(0);  // DMA for tile kt arrived (B always; A-h if kt>=8)
    bar();     // publish; prior-tile reads retired
    const int nt2 = kt + 1;
    const bool hasNext = nt2 < NT;
    const bool nextX = nt2 < 8;
    if (hasNext && nextX) loadX(nt2);   // early f32 issue (T14)
    if (hasNext) stageB(nt2);
    if (hasNext && !nextX) stageAH(nt2);
    const char* pa = smem + (kt & 1) * 40960;
    const char* pb = pa + 16384;
#pragma unroll
    for (int ks = 0; ks < 2; ++ks) {
      bf16x8 av[4], bv[6];
      const int cb = ks * 64 + kc0;
#pragma unroll
      for (int fm = 0; fm < 4; ++fm) {
        const int r = ar0 + fm * 16;
        av[fm] = *(const bf16x8*)(pa + r * 128 + (cb ^ ((r & 7) << 4)));
      }
#pragma unroll
      for (int fn = 0; fn < 6; ++fn) {
        const int r = (fn >> 1) * 64 + wn * 32 + (fn & 1) * 16 + (lane & 15);
        bv[fn] = *(const bf16x8*)(pb + r * 128 + (cb ^ ((r & 7) << 4)));
      }
      __builtin_amdgcn_s_setprio(1);
#pragma unroll
      for (int fn = 0; fn < 6; ++fn) {
        const int ai = (fn < 4) ? fn : NS + (fn - 4);  // compile-time (fn unrolled)
#pragma unroll
        for (int fm = 0; fm < 4; ++fm)
          acc[fm][ai] = __builtin_amdgcn_mfma_f32_16x16x32_bf16(av[fm], bv[fn],
                                                               acc[fm][ai], 0, 0, 0);
      }
      __builtin_amdgcn_s_setprio(0);
    }
    if (hasNext && nextX) { writeX(nt2); LGKM0; }  // publish before next bar
  };

  // prologue: tile 0 (X): reg-stage synchronously, then B DMA
  loadX(0);
  writeX(0);  // compiler inserts vmcnt for xv
  LGKM0;
  stageB(0);

  for (int kt = 0; kt < 8; ++kt) do_tile(kt, ICt<4>{});              // x half: i_n
  if constexpr (!FIRST)
    for (int kt = 8; kt < 16; ++kt) do_tile(kt, ICt<6>{});           // h half: h_n

  // epilogue: gate math (C/D map col=lane&15, row=(lane>>4)*4+j)
  const int erow = (lane >> 4) * 4, ecol = lane & 15;
#pragma unroll
  for (int e = 0; e < 2; ++e) {
    const int d = bn * 64 + wn * 32 + e * 16 + ecol;
    const float br = bih[d] + bhh[d];
    const float bz = bih[512 + d] + bhh[512 + d];
    const float bi = bih[1024 + d];
    const float bh = bhh[1024 + d];
#pragma unroll
    for (int fm = 0; fm < 4; ++fm)
#pragma unroll
      for (int j = 0; j < 4; ++j) {
        const int row = bm * 128 + wm * 64 + fm * 16 + erow + j;
        const size_t off = (size_t)row * 512 + d;
        const float rv = sigmf(acc[fm][0 + e][j] + br);
        const float zv = sigmf(acc[fm][2 + e][j] + bz);
        const float nv = tanhf_(acc[fm][4 + e][j] + bi + rv * (acc[fm][6 + e][j] + bh));
        float hv = (1.0f - zv) * nv;
        if constexpr (!FIRST) hv += zv * bf2f(H[off]);
        outB[off] = f2bf(hv);
      }
  }
}

// ================= mixed kernel: out = [h | x_prev] @ [w1|w2]^T =================
// Block 128 x 128; 4 waves 2m x 2n; wave 64 x 64. LDS 2 x 32KB = 64KB.
// kt<8 = h (bf16 DMA); kt>=8 = x_prev (f32 reg-staged).
template <int WF>
__global__ __launch_bounds__(256, 2) void mixed_gemm(
    const unsigned short* __restrict__ Hb, const float* __restrict__ Xf,
    const unsigned short* __restrict__ Wm,
    unsigned short* __restrict__ outB, float* __restrict__ outF) {
  __shared__ char smem[65536];
  const int t = threadIdx.x;
  const int lane = t & 63, wid = t >> 6;
  const int wm = wid >> 1, wn = wid & 1;
  const int xcd = blockIdx.x & 7, ixc = blockIdx.x >> 3;  // grid 1024
  const int bm = xcd * 32 + (ixc >> 2);  // 256 m-blocks
  const int bn = ixc & 3;                // 4 n-blocks of 128

  f32x4 acc[4][4];
  const f32x4 z4 = {0.f, 0.f, 0.f, 0.f};
#pragma unroll
  for (int a = 0; a < 4; ++a)
#pragma unroll
    for (int b = 0; b < 4; ++b) acc[a][b] = z4;

  const int trow = t >> 3;
  const int tswz = ((t & 7) * 16) ^ ((trow & 7) << 4);
  int hsrc[4], bsrc[4], ldsx[4], xsrc[4];
#pragma unroll
  for (int i = 0; i < 4; ++i) {
    hsrc[i] = (bm * 128 + i * 32 + trow) * 1024 + tswz;
    xsrc[i] = (bm * 128 + i * 32 + trow) * 2048 + (t & 7) * 32;
    ldsx[i] = (i * 32 + trow) * 128 + tswz;
    bsrc[i] = (bn * 128 + i * 32 + trow) * 2048 + tswz;
  }
  const char* Hc = (const char*)Hb;
  const char* Xc = (const char*)Xf;
  const char* Wc = (const char*)Wm;

  auto stageB = [&](int tt) {
    const char* Bb = Wc + tt * 128;
    char* dst = smem + (tt & 1) * 32768 + 16384;
#pragma unroll
    for (int j = 0; j < 4; ++j)
      __builtin_amdgcn_global_load_lds((const AS1 void*)(Bb + bsrc[j]),
                                       (AS3 void*)(dst + j * 4096 + t * 16), 16, 0, 0);
  };
  auto stageAH = [&](int tt) {  // h half (tt < 8)
    const char* Ab = Hc + tt * 128;
    char* dst = smem + (tt & 1) * 32768;
#pragma unroll
    for (int i = 0; i < 4; ++i)
      __builtin_amdgcn_global_load_lds((const AS1 void*)(Ab + hsrc[i]),
                                       (AS3 void*)(dst + i * 4096 + t * 16), 16, 0, 0);
  };

  float4 xv[4][2];
  auto loadX = [&](int tt) {  // x half (tt >= 8)
#pragma unroll
    for (int i = 0; i < 4; ++i) {
      const char* p = Xc + xsrc[i] + (tt - 8) * 256;
      xv[i][0] = *(const float4*)p;
      xv[i][1] = *(const float4*)(p + 16);
    }
  };
  auto writeX = [&](int tt) {
    char* dst = smem + (tt & 1) * 32768;
#pragma unroll
    for (int i = 0; i < 4; ++i) {
      int4 w;
      w.x = (int)cvtpk(xv[i][0].x, xv[i][0].y);
      w.y = (int)cvtpk(xv[i][0].z, xv[i][0].w);
      w.z = (int)cvtpk(xv[i][1].x, xv[i][1].y);
      w.w = (int)cvtpk(xv[i][1].z, xv[i][1].w);
      *(int4*)(dst + ldsx[i]) = w;
    }
  };

  const int ar0 = wm * 64 + (lane & 15);
  const int br0 = wn * 64 + (lane & 15);
  const int kc0 = (lane >> 4) * 16;

  // prologue: tile 0 = h DMA + B DMA
  stageAH(0);
  stageB(0);

  for (int kt = 0; kt < 16; ++kt) {
    VMCNT(0);
    bar();
    const int nt2 = kt + 1;
    const bool hasNext = nt2 < 16;
    const bool nextX = nt2 >= 8;
    if (hasNext && nextX) loadX(nt2);
    if (hasNext) stageB(nt2);
    if (hasNext && !nextX) stageAH(nt2);
    const char* pa = smem + (kt & 1) * 32768;
    const char* pb = pa + 16384;
#pragma unroll
    for (int ks = 0; ks < 2; ++ks) {
      bf16x8 av[4], bv[4];
      const int cb = ks * 64 + kc0;
#pragma unroll
      for (int fm = 0; fm < 4; ++fm) {
        const int r = ar0 + fm * 16;
        av[fm] = *(const bf16x8*)(pa + r * 128 + (cb ^ ((r & 7) << 4)));
      }
#pragma unroll
      for (int fn = 0; fn < 4; ++fn) {
        const int r = br0 + fn * 16;
        bv[fn] = *(const bf16x8*)(pb + r * 128 + (cb ^ ((r & 7) << 4)));
      }
      __builtin_amdgcn_s_setprio(1);
#pragma unroll
      for (int fn = 0; fn < 4; ++fn)
#pragma unroll
        for (int fm = 0; fm < 4; ++fm)
          acc[fm][fn] = __builtin_amdgcn_mfma_f32_16x16x32_bf16(av[fm], bv[fn],
                                                               acc[fm][fn], 0, 0, 0);
      __builtin_amdgcn_s_setprio(0);
    }
    if (hasNext && nextX) { writeX(nt2); LGKM0; }
  }

  const int erow = (lane >> 4) * 4, ecol = lane & 15;
#pragma unroll
  for (int fm = 0; fm < 4; ++fm)
#pragma unroll
    for (int fn = 0; fn < 4; ++fn) {
      const int col = bn * 128 + wn * 64 + fn * 16 + ecol;
#pragma unroll
      for (int j = 0; j < 4; ++j) {
        const int row = bm * 128 + wm * 64 + fm * 16 + erow + j;
        const size_t off = (size_t)row * 512 + col;
        const float v = acc[fm][fn][j];
        if constexpr (WF) outF[off] = v;
        else              outB[off] = f2bf(v);
      }
    }
}

extern "C" void kernel_launch(void* const* d_in, const int* in_sizes, int n_in,
                              void* d_out, int out_size, void* d_ws, size_t ws_size,
                              hipStream_t stream) {
  const float* x   = (const float*)d_in[0];
  const float* wih = (const float*)d_in[1];
  const float* whh = (const float*)d_in[2];
  const float* bih = (const float*)d_in[3];
  const float* bhh = (const float*)d_in[4];
  const float* w1  = (const float*)d_in[5];
  const float* w2  = (const float*)d_in[6];

  char* ws = (char*)d_ws;
  const size_t bd2 = (size_t)BD * 2;
  unsigned short* hb[2] = {(unsigned short*)ws, (unsigned short*)(ws + bd2)};  // 32 MB each
  unsigned short* Wg = (unsigned short*)(ws + 2 * bd2);  // 3 MB
  unsigned short* Wm = Wg + 1536 * 1024;                 // 1 MB

  prep_w<<<8192, 256, 0, stream>>>(wih, whh, w1, w2, Wg, Wm);

  // step 0: h = 0 -> X-half only
  gru_gates<1><<<2048, 256, 0, stream>>>(x, nullptr, Wg, bih, bhh, hb[1]);
  int hp = 1;
  for (int i = 1; i < 8; ++i) {
    const float* xi = x + (size_t)i * BD;
    gru_gates<0><<<2048, 256, 0, stream>>>(xi, hb[hp], Wg, bih, bhh, hb[hp ^ 1]);
    hp ^= 1;
    if (i & 1) {
      const float* xprev = x + (size_t)(i - 1) * BD;
      if (i == 7)
        mixed_gemm<1><<<1024, 256, 0, stream>>>(hb[hp], xprev, Wm, nullptr, (float*)d_out);
      else
        mixed_gemm<0><<<1024, 256, 0, stream>>>(hb[hp], xprev, Wm, hb[hp ^ 1], nullptr);
      if (i != 7) hp ^= 1;
    }
  }
}